// Round 6
// baseline (478.484 us; speedup 1.0000x reference)
//
#include <hip/hip_runtime.h>
#include <math.h>

// ---------------- problem constants ----------------
constexpr int SEQ   = 2048;   // L
constexpr int HID   = 2048;
constexpr int NHQ   = 16;
constexpr int NHKV  = 4;
constexpr int GQ    = NHQ / NHKV;   // 4
constexpr int DH    = 128;
constexpr int CKS   = 32;     // compress window
constexpr int CKST  = 16;     // compress stride
constexpr int NCMP  = (SEQ - CKS) / CKST + 1;  // 127
constexpr int BSZ   = 64;     // selection block
constexpr int NTOP  = 16;
constexpr int NBLK  = SEQ / BSZ;   // 32
constexpr int MBB   = BSZ / CKST;  // 4
constexpr int WINW  = 512;
constexpr int CKD   = CKS * DH;    // 4096 = compress GEMM K
constexpr int NQKV  = HID + 2 * NHKV * DH;  // 3072 fused projection width
constexpr float SCALE = 0.08838834764831845f;  // 1/sqrt(128)

typedef __attribute__((ext_vector_type(8))) short short8;     // 8 bf16 (4 VGPRs)
typedef __attribute__((ext_vector_type(4))) float f32x4;

static __device__ __forceinline__ unsigned short f2bf(float f) {
  unsigned u = __builtin_bit_cast(unsigned, f);
  u = (u + 0x7fffu + ((u >> 16) & 1u)) >> 16;
  return (unsigned short)u;
}
static __device__ __forceinline__ float bf2f(unsigned short u) {
  unsigned v = ((unsigned)u) << 16;
  return __builtin_bit_cast(float, v);
}
// async global->LDS 16B: lane i writes lds_base + i*16
static __device__ __forceinline__ void gload_lds16(const unsigned short* g, unsigned short* l) {
  __builtin_amdgcn_global_load_lds((const __attribute__((address_space(1))) unsigned int*)g,
                                   (__attribute__((address_space(3))) unsigned int*)l, 16, 0, 0);
}

// ---------------- fp32 -> bf16 flat convert ----------------
__global__ __launch_bounds__(256) void conv_bf_kernel(const float* __restrict__ in,
                                                      unsigned short* __restrict__ out) {
  const size_t u = (size_t)blockIdx.x * 256 + threadIdx.x;
  out[u] = f2bf(in[u]);
}

// ---------------- fp32 [K][N] -> bf16 [N][K] tiled transpose (batched over z) ----------------
__global__ __launch_bounds__(256) void transpose_bf_kernel(const float* __restrict__ in,
                                                           unsigned short* __restrict__ out,
                                                           int K, int N) {
  __shared__ float tile[32][33];
  const int tx = threadIdx.x, ty = threadIdx.y;  // 32 x 8
  const int n0 = blockIdx.x * 32, k0 = blockIdx.y * 32;
  const size_t zo = (size_t)blockIdx.z * K * N;
  const float* inz = in + zo;
  unsigned short* outz = out + zo;
#pragma unroll
  for (int r = 0; r < 4; ++r)
    tile[ty + 8 * r][tx] = inz[(size_t)(k0 + ty + 8 * r) * N + n0 + tx];
  __syncthreads();
#pragma unroll
  for (int r = 0; r < 4; ++r)
    outz[(size_t)(n0 + ty + 8 * r) * K + k0 + tx] = f2bf(tile[tx][ty + 8 * r]);
}

// ============ m97-style GEMM core: glds staging, swizzled chunks, LDS double-buffer ============
// LDS tile layout: 512 chunks of 16B. chunk u <-> row r = u>>2, logical k-chunk e = (u&3)^((r>>1)&3).
// Fragment (row, quad) lives at physical chunk row*4 + (quad ^ ((row>>1)&3))  [2-way banks = free].
// 128x128 tile, BK=32; 256 thr = 4 waves; wave w rows [w*32, w*32+32).
__global__ __launch_bounds__(256) void gemm_bf16_128(const unsigned short* __restrict__ A,
                                                     const unsigned short* __restrict__ Bt,
                                                     float* __restrict__ C,
                                                     int M, int N, int K) {
  __shared__ __align__(16) unsigned short As[2][128 * 32];
  __shared__ __align__(16) unsigned short Bs[2][128 * 32];
  const int t = threadIdx.x;
  const int w = t >> 6, lane = t & 63, col = lane & 15, quad = lane >> 4;
  const int m0 = blockIdx.y * 128, n0 = blockIdx.x * 128;
  const int uA0 = (w * 2 + 0) * 64 + lane;
  const int uA1 = (w * 2 + 1) * 64 + lane;
  const int r0 = uA0 >> 2, e0 = (uA0 & 3) ^ ((r0 >> 1) & 3);
  const int r1 = uA1 >> 2, e1 = (uA1 & 3) ^ ((r1 >> 1) & 3);
  const unsigned short* gA0 = A + (size_t)(m0 + r0) * K + e0 * 8;
  const unsigned short* gA1 = A + (size_t)(m0 + r1) * K + e1 * 8;
  const unsigned short* gB0 = Bt + (size_t)(n0 + r0) * K + e0 * 8;
  const unsigned short* gB1 = Bt + (size_t)(n0 + r1) * K + e1 * 8;
  f32x4 acc[2][8];
#pragma unroll
  for (int mi = 0; mi < 2; ++mi)
#pragma unroll
    for (int ni = 0; ni < 8; ++ni) acc[mi][ni] = f32x4{0.f, 0.f, 0.f, 0.f};

  const int S = K / 32;
  // stage step s into buf s&1
  auto stage = [&](int s) {
    const int k0 = s * 32;
    const int b = s & 1;
    gload_lds16(gA0 + k0, &As[b][(w * 2 + 0) * 512]);
    gload_lds16(gA1 + k0, &As[b][(w * 2 + 1) * 512]);
    gload_lds16(gB0 + k0, &Bs[b][(w * 2 + 0) * 512]);
    gload_lds16(gB1 + k0, &Bs[b][(w * 2 + 1) * 512]);
  };
  stage(0);
  for (int s = 0; s < S; ++s) {
    __syncthreads();               // buf s&1 ready; prior compute done
    if (s + 1 < S) stage(s + 1);   // prefetch overlaps compute below
    const unsigned short* as = As[s & 1];
    const unsigned short* bs = Bs[s & 1];
    short8 af[2], bfr[8];
#pragma unroll
    for (int mi = 0; mi < 2; ++mi) {
      const int row = w * 32 + mi * 16 + col;
      af[mi] = *(const short8*)&as[(row * 4 + (quad ^ ((row >> 1) & 3))) * 8];
    }
#pragma unroll
    for (int ni = 0; ni < 8; ++ni) {
      const int row = ni * 16 + col;
      bfr[ni] = *(const short8*)&bs[(row * 4 + (quad ^ ((row >> 1) & 3))) * 8];
    }
#pragma unroll
    for (int mi = 0; mi < 2; ++mi)
#pragma unroll
      for (int ni = 0; ni < 8; ++ni)
        acc[mi][ni] = __builtin_amdgcn_mfma_f32_16x16x32_bf16(af[mi], bfr[ni], acc[mi][ni], 0, 0, 0);
  }
#pragma unroll
  for (int mi = 0; mi < 2; ++mi)
#pragma unroll
    for (int ni = 0; ni < 8; ++ni)
#pragma unroll
      for (int r = 0; r < 4; ++r)
        C[(size_t)(m0 + w * 32 + mi * 16 + quad * 4 + r) * N + n0 + ni * 16 + col] = acc[mi][ni][r];
}

// ---------------- compress A-build from fused qkv: Ak/Av[h][128][4096] bf16 ----------------
__global__ __launch_bounds__(256) void abuild_kernel(const float* __restrict__ qkv,
                                                     const float* __restrict__ pe,
                                                     unsigned short* __restrict__ Ak,
                                                     unsigned short* __restrict__ Av) {
  const size_t u = (size_t)blockIdx.x * 256 + threadIdx.x;  // < 4*128*4096
  const int h = (int)(u >> 19);
  const int rem = (int)(u & 524287);
  const int n = rem >> 12;
  const int e = rem & 4095;
  const int s = e >> 7;
  const int d = e & 127;
  int row = n * CKST + s; if (row > SEQ - 1) row = SEQ - 1;  // pad row (n=127 unused)
  const float* base = qkv + (size_t)row * NQKV + h * DH + d;
  Ak[u] = f2bf(base[HID] + pe[((size_t)h * CKS + s) * DH + d]);
  Av[u] = f2bf(base[HID + NHKV * DH]);
}

// ---------------- compress GEMM: split-K 16 chunks, z = mat*64 + h*16 + kc, glds staging ---------
__global__ __launch_bounds__(256) void compress_gemm(const unsigned short* __restrict__ Ak,
                                                     const unsigned short* __restrict__ Av,
                                                     const unsigned short* __restrict__ WckT,
                                                     const unsigned short* __restrict__ WcvT,
                                                     float* __restrict__ Cpart) {
  __shared__ __align__(16) unsigned short As[2][128 * 32];
  __shared__ __align__(16) unsigned short Bs[2][128 * 32];
  const int z = blockIdx.x;
  const int mat = z >> 6;
  const int h = (z >> 4) & 3;
  const int kc = z & 15;
  const unsigned short* A  = (mat ? Av : Ak)     + (size_t)h * 128 * CKD;
  const unsigned short* Bt = (mat ? WcvT : WckT) + (size_t)h * DH * CKD;
  float* Cout = Cpart + (size_t)z * 128 * 128;
  const int t = threadIdx.x;
  const int w = t >> 6, lane = t & 63, col = lane & 15, quad = lane >> 4;
  const int uA0 = (w * 2 + 0) * 64 + lane;
  const int uA1 = (w * 2 + 1) * 64 + lane;
  const int r0 = uA0 >> 2, e0 = (uA0 & 3) ^ ((r0 >> 1) & 3);
  const int r1 = uA1 >> 2, e1 = (uA1 & 3) ^ ((r1 >> 1) & 3);
  const int kbase = kc * 256;
  const unsigned short* gA0 = A + (size_t)r0 * CKD + kbase + e0 * 8;
  const unsigned short* gA1 = A + (size_t)r1 * CKD + kbase + e1 * 8;
  const unsigned short* gB0 = Bt + (size_t)r0 * CKD + kbase + e0 * 8;
  const unsigned short* gB1 = Bt + (size_t)r1 * CKD + kbase + e1 * 8;
  f32x4 acc[2][8];
#pragma unroll
  for (int mi = 0; mi < 2; ++mi)
#pragma unroll
    for (int ni = 0; ni < 8; ++ni) acc[mi][ni] = f32x4{0.f, 0.f, 0.f, 0.f};
  auto stage = [&](int s) {
    const int k0 = s * 32;
    const int b = s & 1;
    gload_lds16(gA0 + k0, &As[b][(w * 2 + 0) * 512]);
    gload_lds16(gA1 + k0, &As[b][(w * 2 + 1) * 512]);
    gload_lds16(gB0 + k0, &Bs[b][(w * 2 + 0) * 512]);
    gload_lds16(gB1 + k0, &Bs[b][(w * 2 + 1) * 512]);
  };
  stage(0);
  for (int s = 0; s < 8; ++s) {
    __syncthreads();
    if (s + 1 < 8) stage(s + 1);
    const unsigned short* as = As[s & 1];
    const unsigned short* bs = Bs[s & 1];
    short8 af[2], bfr[8];
#pragma unroll
    for (int mi = 0; mi < 2; ++mi) {
      const int row = w * 32 + mi * 16 + col;
      af[mi] = *(const short8*)&as[(row * 4 + (quad ^ ((row >> 1) & 3))) * 8];
    }
#pragma unroll
    for (int ni = 0; ni < 8; ++ni) {
      const int row = ni * 16 + col;
      bfr[ni] = *(const short8*)&bs[(row * 4 + (quad ^ ((row >> 1) & 3))) * 8];
    }
#pragma unroll
    for (int mi = 0; mi < 2; ++mi)
#pragma unroll
      for (int ni = 0; ni < 8; ++ni)
        acc[mi][ni] = __builtin_amdgcn_mfma_f32_16x16x32_bf16(af[mi], bfr[ni], acc[mi][ni], 0, 0, 0);
  }
#pragma unroll
  for (int mi = 0; mi < 2; ++mi)
#pragma unroll
    for (int ni = 0; ni < 8; ++ni)
#pragma unroll
      for (int r = 0; r < 4; ++r)
        Cout[(size_t)(w * 32 + mi * 16 + quad * 4 + r) * 128 + ni * 16 + col] = acc[mi][ni][r];
}

// ---------------- compress reduce (16 chunks) + fused ck-RoPE -> ckbf / cvbf ----------------
__global__ __launch_bounds__(256) void compress_reduce_rope(const float* __restrict__ Cpart,
                                                            unsigned short* __restrict__ ckbf,
                                                            unsigned short* __restrict__ cvbf) {
  const unsigned u = blockIdx.x * 256 + threadIdx.x;  // < 32768 + 65536
  if (u < 32768) {  // ck with rope: (h, n, d<64)
    const int h = u >> 13;
    const int rem = u & 8191;
    const int n = rem >> 6;
    const int d = rem & 63;
    const size_t b0 = ((size_t)(h * 16) << 14) + n * 128 + d;
    float x1 = 0.f, x2 = 0.f;
#pragma unroll
    for (int kc = 0; kc < 16; ++kc) {
      x1 += Cpart[b0 + (size_t)kc * 16384];
      x2 += Cpart[b0 + 64 + (size_t)kc * 16384];
    }
    float inv = powf(10000.f, -(float)d / 64.f);
    float ang = (float)(n * CKST) * inv;
    float c, s;
    sincosf(ang, &s, &c);
    const size_t o = ((size_t)n * NHKV + h) * DH + d;
    ckbf[o]      = f2bf(x1 * c - x2 * s);
    ckbf[o + 64] = f2bf(x2 * c + x1 * s);
  } else {  // cv: (h, n, d)
    const unsigned u2 = u - 32768;
    const int h = u2 >> 14;
    const int rem = u2 & 16383;
    const size_t b0 = ((size_t)(64 + h * 16) << 14) + rem;
    float s = 0.f;
#pragma unroll
    for (int kc = 0; kc < 16; ++kc) s += Cpart[b0 + (size_t)kc * 16384];
    const int n = rem >> 7, d = rem & 127;
    cvbf[((size_t)n * NHKV + h) * DH + d] = f2bf(s);
  }
}

// ---------------- gate = sigmoid(x @ Wg) ----------------
__global__ __launch_bounds__(128) void gate_kernel(const float* __restrict__ x,
                                                   const float* __restrict__ Wg,
                                                   float* __restrict__ gate) {
  const int i = blockIdx.x;
  const int t = threadIdx.x;
  float a0 = 0.f, a1 = 0.f, a2 = 0.f;
  for (int kk = t; kk < HID; kk += 128) {
    float xv = x[(size_t)i * HID + kk];
    a0 += xv * Wg[kk * 3 + 0];
    a1 += xv * Wg[kk * 3 + 1];
    a2 += xv * Wg[kk * 3 + 2];
  }
#pragma unroll
  for (int s = 1; s < 64; s <<= 1) {
    a0 += __shfl_xor(a0, s);
    a1 += __shfl_xor(a1, s);
    a2 += __shfl_xor(a2, s);
  }
  __shared__ float part[2][3];
  if ((t & 63) == 0) { part[t >> 6][0] = a0; part[t >> 6][1] = a1; part[t >> 6][2] = a2; }
  __syncthreads();
  if (t == 0) {
    gate[i * 3 + 0] = 1.f / (1.f + expf(-(part[0][0] + part[1][0])));
    gate[i * 3 + 1] = 1.f / (1.f + expf(-(part[0][1] + part[1][1])));
    gate[i * 3 + 2] = 1.f / (1.f + expf(-(part[0][2] + part[1][2])));
  }
}

// ---------------- RoPE (reads fused qkv, stride NQKV) ----------------
__global__ __launch_bounds__(64) void rope_q_kernel(const float* __restrict__ qkv,
                                                    unsigned short* __restrict__ qbf) {
  const int rh = blockIdx.x;
  const int r = rh >> 4;
  const int hq = rh & 15;
  const int t = threadIdx.x;
  const float* p = qkv + (size_t)r * NQKV + hq * DH;
  float x1 = p[t], x2 = p[t + 64];
  float inv = powf(10000.f, -(float)t / 64.f);
  float ang = (float)r * inv;
  float c, s;
  sincosf(ang, &s, &c);
  qbf[(size_t)rh * DH + t]      = f2bf(x1 * c - x2 * s);
  qbf[(size_t)rh * DH + t + 64] = f2bf(x2 * c + x1 * s);
}
__global__ __launch_bounds__(64) void rope_k_kernel(const float* __restrict__ qkv,
                                                    unsigned short* __restrict__ kbf) {
  const int rh = blockIdx.x;
  const int r = rh >> 2;
  const int h = rh & 3;
  const int t = threadIdx.x;
  const float* p = qkv + (size_t)r * NQKV + HID + h * DH;
  float x1 = p[t], x2 = p[t + 64];
  float inv = powf(10000.f, -(float)t / 64.f);
  float ang = (float)r * inv;
  float c, s;
  sincosf(ang, &s, &c);
  kbf[(size_t)rh * DH + t]      = f2bf(x1 * c - x2 * s);
  kbf[(size_t)rh * DH + t + 64] = f2bf(x2 * c + x1 * s);
}
// ---------------- V transpose: qkv v-part [i][h*128+d] -> vT[h][d][i] bf16 ----------------
__global__ __launch_bounds__(256) void vtrans_kernel(const float* __restrict__ qkv,
                                                     unsigned short* __restrict__ vT) {
  __shared__ float tile[32][33];
  const int tx = threadIdx.x, ty = threadIdx.y;  // 32 x 8
  const int ix = blockIdx.x * 32;   // seq
  const int dx = blockIdx.y * 32;   // d
  const int h = blockIdx.z;
#pragma unroll
  for (int r = 0; r < 4; ++r)
    tile[ty + 8 * r][tx] = qkv[(size_t)(ix + ty + 8 * r) * NQKV + HID + NHKV * DH + h * DH + dx + tx];
  __syncthreads();
#pragma unroll
  for (int r = 0; r < 4; ++r)
    vT[(size_t)(h * DH + dx + ty + 8 * r) * SEQ + ix + tx] = f2bf(tile[tx][ty + 8 * r]);
}

// ---------------- MFMA compressed attention + pscore + top-k bitmask ----------------
constexpr int CSTR = 136;
__global__ __launch_bounds__(256) void cmp_attn_mfma(const unsigned short* __restrict__ qbf,
                                                     const unsigned short* __restrict__ ckbf,
                                                     const unsigned short* __restrict__ cvbf,
                                                     unsigned short* __restrict__ cmpobf,
                                                     unsigned* __restrict__ smask) {
  __shared__ __align__(16) unsigned short cks[64 * CSTR];
  __shared__ __align__(16) unsigned short cvts[128 * CSTR];
  __shared__ __align__(16) unsigned short Ps[4][16 * CSTR];
  __shared__ float pscore[16][132];
  const int h = blockIdx.x & 3;
  const int i0 = (blockIdx.x >> 2) * 16;
  const int t = threadIdx.x;
  const int w = t >> 6;
  const int lane = t & 63;
  const int col = lane & 15;
  const int quad = lane >> 4;
  const int iq = i0 + 4 * w + quad;

  short8 qf[4];
  {
    const int qi = i0 + 4 * w + (col >> 2);
    const int g = col & 3;
    const unsigned short* qp = qbf + ((size_t)qi * NHQ + h * GQ + g) * DH + quad * 8;
#pragma unroll
    for (int dc = 0; dc < 4; ++dc) qf[dc] = *(const short8*)(qp + dc * 32);
  }
  if (t < 64) pscore[t >> 2][128 + (t & 3)] = 0.f;
  const int jmax = (iq >= CKS - 1) ? ((iq - (CKS - 1)) >> 4) : -1;

  float sreg[8][4];
  for (int ch = 0; ch < 2; ++ch) {
    if (ch) __syncthreads();
    {
      const int r = t >> 2, c0 = (t & 3) * 32;
      const unsigned short* src = ckbf + ((size_t)(ch * 64 + r) * NHKV + h) * DH + c0;
#pragma unroll
      for (int u = 0; u < 4; ++u)
        *(short8*)&cks[r * CSTR + c0 + u * 8] = *(const short8*)(src + u * 8);
    }
    if (ch == 0) {
      const int j = t >> 1, d0 = (t & 1) * 64;
      const unsigned short* vsrc = cvbf + ((size_t)j * NHKV + h) * DH + d0;
#pragma unroll
      for (int u = 0; u < 16; ++u) {
        if (j == 127) {
#pragma unroll
          for (int dd = 0; dd < 4; ++dd) cvts[(d0 + u * 4 + dd) * CSTR + j] = 0;
        } else {
          const unsigned short* vv = vsrc + u * 4;
#pragma unroll
          for (int dd = 0; dd < 4; ++dd) cvts[(d0 + u * 4 + dd) * CSTR + j] = vv[dd];
        }
      }
    }
    __syncthreads();
#pragma unroll
    for (int tt = 0; tt < 4; ++tt) {
      f32x4 s = f32x4{0.f, 0.f, 0.f, 0.f};
#pragma unroll
      for (int dc = 0; dc < 4; ++dc)
        s = __builtin_amdgcn_mfma_f32_16x16x32_bf16(
            qf[dc], *(const short8*)&cks[(tt * 16 + col) * CSTR + dc * 32 + quad * 8], s, 0, 0, 0);
#pragma unroll
      for (int r = 0; r < 4; ++r) sreg[ch * 4 + tt][r] = s[r];
    }
  }

#pragma unroll
  for (int r = 0; r < 4; ++r) {
    float mx = -INFINITY;
#pragma unroll
    for (int tt = 0; tt < 8; ++tt) {
      const float val = (tt * 16 + col <= jmax) ? sreg[tt][r] * SCALE : -INFINITY;
      sreg[tt][r] = val;
      mx = fmaxf(mx, val);
    }
    mx = fmaxf(mx, __shfl_xor(mx, 1));
    mx = fmaxf(mx, __shfl_xor(mx, 2));
    mx = fmaxf(mx, __shfl_xor(mx, 4));
    mx = fmaxf(mx, __shfl_xor(mx, 8));
    float l = 0.f;
#pragma unroll
    for (int tt = 0; tt < 8; ++tt) {
      const float p = (sreg[tt][r] == -INFINITY) ? 0.f : __expf(sreg[tt][r] - mx);
      sreg[tt][r] = p;
      l += p;
    }
    l += __shfl_xor(l, 1); l += __shfl_xor(l, 2); l += __shfl_xor(l, 4); l += __shfl_xor(l, 8);
    const float rden = 1.f / fmaxf(l, 1e-20f);
#pragma unroll
    for (int tt = 0; tt < 8; ++tt) {
      const float pn = sreg[tt][r] * rden;
      sreg[tt][r] = pn;
      Ps[w][(quad * 4 + r) * CSTR + tt * 16 + col] = f2bf(pn);
    }
  }
#pragma unroll
  for (int tt = 0; tt < 8; ++tt)
    pscore[4 * w + quad][tt * 16 + col] = sreg[tt][0] + sreg[tt][1] + sreg[tt][2] + sreg[tt][3];

  f32x4 acc[8];
#pragma unroll
  for (int dt = 0; dt < 8; ++dt) acc[dt] = f32x4{0.f, 0.f, 0.f, 0.f};
#pragma unroll
  for (int kt = 0; kt < 4; ++kt) {
    short8 ap = *(const short8*)&Ps[w][col * CSTR + kt * 32 + quad * 8];
#pragma unroll
    for (int dt = 0; dt < 8; ++dt)
      acc[dt] = __builtin_amdgcn_mfma_f32_16x16x32_bf16(
          ap, *(const short8*)&cvts[(dt * 16 + col) * CSTR + kt * 32 + quad * 8], acc[dt], 0, 0, 0);
  }
#pragma unroll
  for (int dt = 0; dt < 8; ++dt)
#pragma unroll
    for (int r = 0; r < 4; ++r)
      cmpobf[((size_t)iq * NHQ + h * GQ + r) * DH + dt * 16 + col] = f2bf(acc[dt][r]);

  __syncthreads();
  if (t < 16) {
    const int i = i0 + t;
    const int qblk = i / BSZ;
    const float offw[5] = {1.f, 2.f, 2.f, 2.f, 1.f};
    float tmp[NBLK];
    for (int b = 0; b < NBLK; ++b) {
      float s = 0.f;
#pragma unroll
      for (int o = 0; o < 5; ++o) s += pscore[t][b * MBB + o] * offw[o];
      const bool causal = (b <= qblk);
      const bool forced = (b < 1) || ((b > qblk - 2) && causal);
      tmp[b] = causal ? (forced ? INFINITY : s) : -INFINITY;
    }
    unsigned msk = 0;
    for (int s = 0; s < NTOP; ++s) {
      int best = -1;
      float bv = -INFINITY;
      for (int b = 0; b < NBLK; ++b)
        if (tmp[b] > bv) { bv = tmp[b]; best = b; }
      if (best >= 0) { msk |= (1u << best); tmp[best] = -INFINITY; }
    }
    smask[(size_t)i * NHKV + h] = msk;
  }
}

// ---------------- dual-mask flash attention: 64-key tiles, 40KB LDS, 3 blocks/CU ----------------
__global__ __launch_bounds__(256, 3) void nsa_attn_kernel(
    const unsigned short* __restrict__ qbf,
    const unsigned short* __restrict__ kbf,
    const unsigned short* __restrict__ vT,
    const unsigned* __restrict__ smask,
    const float* __restrict__ gate,
    const unsigned short* __restrict__ cmpo,
    unsigned short* __restrict__ outc) {
  __shared__ __align__(16) unsigned short Ks[64 * 128];   // 16 KB
  __shared__ __align__(16) unsigned short Vs[128 * 64];   // 16 KB
  __shared__ __align__(16) unsigned short Ps[4][16 * 64]; // 8 KB (per-wave P)
  const int bx = blockIdx.x;
  const int qt = 127 - (bx >> 2);   // big-work blocks first
  const int h = bx & 3;
  const int i0 = qt * 16;
  const int t = threadIdx.x;
  const int w = t >> 6;
  const int lane = t & 63;
  const int col = lane & 15;
  const int quad = lane >> 4;
  const int i0w = i0 + w * 4;
  const int i_lane = i0w + quad;

  short8 qf[4];
  {
    const int qi = i0w + (col >> 2);
    const int g = col & 3;
    const unsigned short* qp = qbf + (((size_t)qi * NHQ) + h * 4 + g) * DH + quad * 8;
#pragma unroll
    for (int dc = 0; dc < 4; ++dc) qf[dc] = *(const short8*)(qp + dc * 32);
  }
  const unsigned mymask = smask[(size_t)i_lane * NHKV + h];

  // block tile mask: OR of 16 query masks | window range (all causal)
  unsigned bmask;
  {
    unsigned mm = smask[(size_t)(i0 + col) * NHKV + h];
    mm |= __shfl_xor(mm, 1); mm |= __shfl_xor(mm, 2);
    mm |= __shfl_xor(mm, 4); mm |= __shfl_xor(mm, 8);
    const int whi = (i0 + 15) >> 6;
    int wl = i0 - WINW; wl = (wl < 0) ? 0 : (wl >> 6);
    const unsigned hibits = (whi >= 31) ? 0xffffffffu : ((1u << (whi + 1)) - 1u);
    bmask = mm | (hibits & ~((1u << wl) - 1u));
  }

  f32x4 accS[8], accW[8];
#pragma unroll
  for (int dt = 0; dt < 8; ++dt) { accS[dt] = f32x4{0.f,0.f,0.f,0.f}; accW[dt] = f32x4{0.f,0.f,0.f,0.f}; }
  float mS[4], mW[4], lS[4], lW[4];
#pragma unroll
  for (int r = 0; r < 4; ++r) { mS[r] = -INFINITY; mW[r] = -INFINITY; lS[r] = 0.f; lW[r] = 0.f; }

  // async staging (swizzled: chunk c stored at physical c ^ (row&7))
  auto stageK = [&](int b) {
#pragma unroll
    for (int qq = 0; qq < 4; ++qq) {
      const int q = w * 4 + qq;
      const int u = q * 64 + lane;
      const int r = u >> 4;
      const int c = (u & 15) ^ (r & 7);
      const unsigned short* g = kbf + ((size_t)((b * 64 + r) * NHKV + h)) * DH + c * 8;
      gload_lds16(g, &Ks[q * 512]);
    }
  };
  auto stageV = [&](int b) {
#pragma unroll
    for (int qq = 0; qq < 4; ++qq) {
      const int q = w * 4 + qq;
      const int u = q * 64 + lane;
      const int r = u >> 3;
      const int c = (u & 7) ^ (r & 7);
      const unsigned short* g = vT + ((size_t)(h * DH + r)) * SEQ + b * 64 + c * 8;
      gload_lds16(g, &Vs[q * 512]);
    }
  };

  unsigned tmw = bmask;
  bool first = true;
  while (tmw) {
    const int cur = __builtin_ctz(tmw);
    tmw &= tmw - 1;
    if (!first) __syncthreads();     // prev compute done; K/V free
    first = false;
    stageK(cur);
    stageV(cur);
    __syncthreads();                 // staged data visible

    const int j0 = cur * 64;
    const bool wact = (j0 <= i0w + 3);
    const bool selbit = wact && ((mymask >> cur) & 1u);
    const bool selAny = (__ballot(selbit) != 0ull);
    const bool winAny = wact && (j0 + 63 >= i0w - WINW);

    f32x4 sc[4];
    auto softmax_p = [&](bool forsel, float* mrun, float* lrun, f32x4* acc) {
#pragma unroll
      for (int r = 0; r < 4; ++r) {
        float vv[4];
        float tmax = -INFINITY;
#pragma unroll
        for (int kt = 0; kt < 4; ++kt) {
          const int j = j0 + kt * 16 + col;
          const bool act = (j <= i_lane) && (forsel ? selbit : (j >= i_lane - WINW));
          vv[kt] = act ? sc[kt][r] * SCALE : -INFINITY;
          tmax = fmaxf(tmax, vv[kt]);
        }
        tmax = fmaxf(tmax, __shfl_xor(tmax, 1));
        tmax = fmaxf(tmax, __shfl_xor(tmax, 2));
        tmax = fmaxf(tmax, __shfl_xor(tmax, 4));
        tmax = fmaxf(tmax, __shfl_xor(tmax, 8));
        const float mn = fmaxf(mrun[r], tmax);
        const float a = (mn == -INFINITY) ? 1.f : __expf(mrun[r] - mn);
        float ls = 0.f;
        const int m = quad * 4 + r;
#pragma unroll
        for (int kt = 0; kt < 4; ++kt) {
          const float pp = (vv[kt] == -INFINITY) ? 0.f : __expf(vv[kt] - mn);
          ls += pp;
          const int n = kt * 16 + col;
          Ps[w][m * 64 + ((((n >> 3) ^ (m & 7))) << 3) + (n & 7)] = f2bf(pp);
        }
        lrun[r] = lrun[r] * a + ls;
        mrun[r] = mn;
#pragma unroll
        for (int dt = 0; dt < 8; ++dt) acc[dt][r] *= a;
      }
    };
    auto pv = [&](f32x4* acc) {
#pragma unroll
      for (int kt2 = 0; kt2 < 2; ++kt2) {
        short8 ap = *(const short8*)&Ps[w][col * 64 + ((((kt2 * 4 + quad) ^ (col & 7))) << 3)];
#pragma unroll
        for (int dt = 0; dt < 8; ++dt) {
          const int rv = dt * 16 + col;
          short8 vfr = *(const short8*)&Vs[rv * 64 + ((((kt2 * 4 + quad) ^ (rv & 7))) << 3)];
          acc[dt] = __builtin_amdgcn_mfma_f32_16x16x32_bf16(ap, vfr, acc[dt], 0, 0, 0);
        }
      }
    };

    if (selAny || winAny) {
#pragma unroll
      for (int kt = 0; kt < 4; ++kt) {
        f32x4 ss = f32x4{0.f, 0.f, 0.f, 0.f};
        const int row = kt * 16 + col;
#pragma unroll
        for (int dc = 0; dc < 4; ++dc) {
          short8 kf = *(const short8*)&Ks[row * 128 + ((((dc * 4 + quad) ^ (col & 7))) << 3)];
          ss = __builtin_amdgcn_mfma_f32_16x16x32_bf16(qf[dc], kf, ss, 0, 0, 0);
        }
        sc[kt] = ss;
      }
      if (selAny) { softmax_p(true, mS, lS, accS); pv(accS); }
      if (winAny) { softmax_p(false, mW, lW, accW); pv(accW); }
    }
  }

  // epilogue
#pragma unroll
  for (int r = 0; r < 4; ++r) {
    float v = lS[r];
    v += __shfl_xor(v, 1); v += __shfl_xor(v, 2); v += __shfl_xor(v, 4); v += __shfl_xor(v, 8);
    lS[r] = v;
    float u = lW[r];
    u += __shfl_xor(u, 1); u += __shfl_xor(u, 2); u += __shfl_xor(u, 4); u += __shfl_xor(u, 8);
    lW[r] = u;
  }
  const float g0 = gate[i_lane * 3 + 0];
  const float g1 = gate[i_lane * 3 + 1];
  const float g2 = gate[i_lane * 3 + 2];
#pragma unroll
  for (int r = 0; r < 4; ++r) {
    const size_t base = ((size_t)i_lane * NHQ + h * 4 + r) * DH;
    const float rls = g1 / lS[r];
    const float rlw = g2 / lW[r];
#pragma unroll
    for (int dt = 0; dt < 8; ++dt) {
      const size_t o = base + dt * 16 + col;
      outc[o] = f2bf(g0 * bf2f(cmpo[o]) + rls * accS[dt][r] + rlw * accW[dt][r]);
    }
  }
}

// ---------------- launcher ----------------
extern "C" void kernel_launch(void* const* d_in, const int* in_sizes, int n_in,
                              void* d_out, int out_size, void* d_ws, size_t ws_size,
                              hipStream_t stream) {
  const float* x   = (const float*)d_in[0];
  const float* Wq  = (const float*)d_in[2];
  const float* Wk  = (const float*)d_in[3];
  const float* Wv  = (const float*)d_in[4];
  const float* Wo  = (const float*)d_in[5];
  const float* Wck = (const float*)d_in[6];
  const float* Wcv = (const float*)d_in[7];
  const float* pe  = (const float*)d_in[8];
  const float* Wg  = (const float*)d_in[9];
  float* out = (float*)d_out;

  unsigned char* p = (unsigned char*)d_ws;
  auto alloc = [&](size_t bytes) { void* r = p; p += (bytes + 255) & ~(size_t)255; return r; };
  float* qkv  = (float*)alloc((size_t)SEQ * NQKV * 4);        // 24MB; later hosts WoT + combbf
  float* gbuf = (float*)alloc((size_t)SEQ * 4 * 4);
  unsigned* smask = (unsigned*)alloc((size_t)SEQ * NHKV * 4);
  unsigned short* ckbf = (unsigned short*)alloc((size_t)128 * NHKV * DH * 2);
  unsigned short* cvbf = (unsigned short*)alloc((size_t)128 * NHKV * DH * 2);
  unsigned short* xbf  = (unsigned short*)alloc((size_t)SEQ * HID * 2);        // 8MB; -> Ak/Av -> cmpobf
  unsigned short* WqkvT = (unsigned short*)alloc((size_t)NQKV * HID * 2);      // 12MB; -> Cpart -> qbf/krbf/vT
  unsigned short* WckT = (unsigned short*)alloc((size_t)NHKV * DH * CKD * 2);  // 4MB
  unsigned short* WcvT = (unsigned short*)alloc((size_t)NHKV * DH * CKD * 2);  // 4MB
  unsigned short* WoT    = (unsigned short*)qkv;                                // 8MB
  unsigned short* combbf = (unsigned short*)qkv + (size_t)NHQ * DH * HID;       // next 8MB
  unsigned short* Ak     = xbf;
  unsigned short* Av     = xbf + (size_t)NHKV * 128 * CKD;
  unsigned short* cmpobf = xbf;
  float* Cpart = (float*)WqkvT;                                  // 8MB over future qbf (dead weights)
  unsigned short* qbf  = WqkvT;                                  // 8MB
  unsigned short* krbf = WqkvT + (size_t)HID * HID;              // 2MB
  unsigned short* vT   = WqkvT + (size_t)(HID + NHKV * DH) * HID;// 2MB

  // convert / transpose weights + x
  conv_bf_kernel<<<(SEQ * HID) / 256, 256, 0, stream>>>(x, xbf);
  transpose_bf_kernel<<<dim3(HID / 32, HID / 32), dim3(32, 8), 0, stream>>>(Wq, WqkvT, HID, HID);
  transpose_bf_kernel<<<dim3((NHKV * DH) / 32, HID / 32), dim3(32, 8), 0, stream>>>(Wk, WqkvT + (size_t)HID * HID, HID, NHKV * DH);
  transpose_bf_kernel<<<dim3((NHKV * DH) / 32, HID / 32), dim3(32, 8), 0, stream>>>(Wv, WqkvT + (size_t)(HID + NHKV * DH) * HID, HID, NHKV * DH);
  transpose_bf_kernel<<<dim3(DH / 32, CKD / 32, NHKV), dim3(32, 8), 0, stream>>>(Wck, WckT, CKD, DH);
  transpose_bf_kernel<<<dim3(DH / 32, CKD / 32, NHKV), dim3(32, 8), 0, stream>>>(Wcv, WcvT, CKD, DH);
  // fused q/k/v projection
  gemm_bf16_128<<<dim3(NQKV / 128, SEQ / 128), 256, 0, stream>>>(xbf, WqkvT, qkv, SEQ, NQKV, HID);
  gate_kernel<<<SEQ, 128, 0, stream>>>(x, Wg, gbuf);
  // compression as GEMM (A-build overwrites dead xbf; Cpart overlays dead WqkvT weights)
  abuild_kernel<<<(NHKV * 128 * CKD) / 256, 256, 0, stream>>>(qkv, pe, Ak, Av);
  compress_gemm<<<128, 256, 0, stream>>>(Ak, Av, WckT, WcvT, Cpart);
  compress_reduce_rope<<<(32768 + 65536) / 256, 256, 0, stream>>>(Cpart, ckbf, cvbf);
  // RoPE + V transpose (overwrite WqkvT/Cpart region after reduce)
  rope_q_kernel<<<SEQ * NHQ, 64, 0, stream>>>(qkv, qbf);
  rope_k_kernel<<<SEQ * NHKV, 64, 0, stream>>>(qkv, krbf);
  vtrans_kernel<<<dim3(SEQ / 32, DH / 32, NHKV), dim3(32, 8), 0, stream>>>(qkv, vT);
  // Wo transpose into dead qkv region (after all qkv consumers)
  transpose_bf_kernel<<<dim3(HID / 32, (NHQ * DH) / 32), dim3(32, 8), 0, stream>>>(Wo, WoT, NHQ * DH, HID);
  // compressed attention + selection
  cmp_attn_mfma<<<(SEQ / 16) * NHKV, 256, 0, stream>>>(qbf, ckbf, cvbf, cmpobf, smask);
  // selected + window attention + gated combine
  nsa_attn_kernel<<<(SEQ / 16) * NHKV, 256, 0, stream>>>(qbf, krbf, vT, smask, gbuf, cmpobf, combbf);
  // output projection
  gemm_bf16_128<<<dim3(HID / 128, SEQ / 128), 256, 0, stream>>>(combbf, WoT, out, SEQ, HID, NHQ * DH);
}

// Round 7
// 420.497 us; speedup vs baseline: 1.1379x; 1.1379x over previous
//
#include <hip/hip_runtime.h>
#include <math.h>

// ---------------- problem constants ----------------
constexpr int SEQ   = 2048;   // L
constexpr int HID   = 2048;
constexpr int NHQ   = 16;
constexpr int NHKV  = 4;
constexpr int GQ    = NHQ / NHKV;   // 4
constexpr int DH    = 128;
constexpr int CKS   = 32;     // compress window
constexpr int CKST  = 16;     // compress stride
constexpr int NCMP  = (SEQ - CKS) / CKST + 1;  // 127
constexpr int BSZ   = 64;     // selection block
constexpr int NTOP  = 16;
constexpr int NBLK  = SEQ / BSZ;   // 32
constexpr int MBB   = BSZ / CKST;  // 4
constexpr int WINW  = 512;
constexpr int CKD   = CKS * DH;    // 4096 = compress GEMM K
constexpr int NQKV  = HID + 2 * NHKV * DH;  // 3072 fused projection width
constexpr float SCALE = 0.08838834764831845f;  // 1/sqrt(128)

typedef __attribute__((ext_vector_type(8))) short short8;     // 8 bf16 (4 VGPRs)
typedef __attribute__((ext_vector_type(4))) float f32x4;

static __device__ __forceinline__ unsigned short f2bf(float f) {
  unsigned u = __builtin_bit_cast(unsigned, f);
  u = (u + 0x7fffu + ((u >> 16) & 1u)) >> 16;
  return (unsigned short)u;
}
static __device__ __forceinline__ float bf2f(unsigned short u) {
  unsigned v = ((unsigned)u) << 16;
  return __builtin_bit_cast(float, v);
}
// async global->LDS 16B: lane i writes lds_base + i*16
static __device__ __forceinline__ void gload_lds16(const unsigned short* g, unsigned short* l) {
  __builtin_amdgcn_global_load_lds((const __attribute__((address_space(1))) unsigned int*)g,
                                   (__attribute__((address_space(3))) unsigned int*)l, 16, 0, 0);
}

// ---------------- fp32 -> bf16 flat convert ----------------
__global__ __launch_bounds__(256) void conv_bf_kernel(const float* __restrict__ in,
                                                      unsigned short* __restrict__ out) {
  const size_t u = (size_t)blockIdx.x * 256 + threadIdx.x;
  out[u] = f2bf(in[u]);
}

// ---------------- fp32 [K][N] -> bf16 [N][K] tiled transpose (batched over z) ----------------
__global__ __launch_bounds__(256) void transpose_bf_kernel(const float* __restrict__ in,
                                                           unsigned short* __restrict__ out,
                                                           int K, int N) {
  __shared__ float tile[32][33];
  const int tx = threadIdx.x, ty = threadIdx.y;  // 32 x 8
  const int n0 = blockIdx.x * 32, k0 = blockIdx.y * 32;
  const size_t zo = (size_t)blockIdx.z * K * N;
  const float* inz = in + zo;
  unsigned short* outz = out + zo;
#pragma unroll
  for (int r = 0; r < 4; ++r)
    tile[ty + 8 * r][tx] = inz[(size_t)(k0 + ty + 8 * r) * N + n0 + tx];
  __syncthreads();
#pragma unroll
  for (int r = 0; r < 4; ++r)
    outz[(size_t)(n0 + ty + 8 * r) * K + k0 + tx] = f2bf(tile[tx][ty + 8 * r]);
}

// ============ m97-style GEMM core: glds staging, swizzled chunks, LDS double-buffer ============
__global__ __launch_bounds__(256) void gemm_bf16_128(const unsigned short* __restrict__ A,
                                                     const unsigned short* __restrict__ Bt,
                                                     float* __restrict__ C,
                                                     int M, int N, int K) {
  __shared__ __align__(16) unsigned short As[2][128 * 32];
  __shared__ __align__(16) unsigned short Bs[2][128 * 32];
  const int t = threadIdx.x;
  const int w = t >> 6, lane = t & 63, col = lane & 15, quad = lane >> 4;
  const int m0 = blockIdx.y * 128, n0 = blockIdx.x * 128;
  const int uA0 = (w * 2 + 0) * 64 + lane;
  const int uA1 = (w * 2 + 1) * 64 + lane;
  const int r0 = uA0 >> 2, e0 = (uA0 & 3) ^ ((r0 >> 1) & 3);
  const int r1 = uA1 >> 2, e1 = (uA1 & 3) ^ ((r1 >> 1) & 3);
  const unsigned short* gA0 = A + (size_t)(m0 + r0) * K + e0 * 8;
  const unsigned short* gA1 = A + (size_t)(m0 + r1) * K + e1 * 8;
  const unsigned short* gB0 = Bt + (size_t)(n0 + r0) * K + e0 * 8;
  const unsigned short* gB1 = Bt + (size_t)(n0 + r1) * K + e1 * 8;
  f32x4 acc[2][8];
#pragma unroll
  for (int mi = 0; mi < 2; ++mi)
#pragma unroll
    for (int ni = 0; ni < 8; ++ni) acc[mi][ni] = f32x4{0.f, 0.f, 0.f, 0.f};

  const int S = K / 32;
  auto stage = [&](int s) {
    const int k0 = s * 32;
    const int b = s & 1;
    gload_lds16(gA0 + k0, &As[b][(w * 2 + 0) * 512]);
    gload_lds16(gA1 + k0, &As[b][(w * 2 + 1) * 512]);
    gload_lds16(gB0 + k0, &Bs[b][(w * 2 + 0) * 512]);
    gload_lds16(gB1 + k0, &Bs[b][(w * 2 + 1) * 512]);
  };
  stage(0);
  for (int s = 0; s < S; ++s) {
    __syncthreads();
    if (s + 1 < S) stage(s + 1);
    const unsigned short* as = As[s & 1];
    const unsigned short* bs = Bs[s & 1];
    short8 af[2], bfr[8];
#pragma unroll
    for (int mi = 0; mi < 2; ++mi) {
      const int row = w * 32 + mi * 16 + col;
      af[mi] = *(const short8*)&as[(row * 4 + (quad ^ ((row >> 1) & 3))) * 8];
    }
#pragma unroll
    for (int ni = 0; ni < 8; ++ni) {
      const int row = ni * 16 + col;
      bfr[ni] = *(const short8*)&bs[(row * 4 + (quad ^ ((row >> 1) & 3))) * 8];
    }
#pragma unroll
    for (int mi = 0; mi < 2; ++mi)
#pragma unroll
      for (int ni = 0; ni < 8; ++ni)
        acc[mi][ni] = __builtin_amdgcn_mfma_f32_16x16x32_bf16(af[mi], bfr[ni], acc[mi][ni], 0, 0, 0);
  }
#pragma unroll
  for (int mi = 0; mi < 2; ++mi)
#pragma unroll
    for (int ni = 0; ni < 8; ++ni)
#pragma unroll
      for (int r = 0; r < 4; ++r)
        C[(size_t)(m0 + w * 32 + mi * 16 + quad * 4 + r) * N + n0 + ni * 16 + col] = acc[mi][ni][r];
}

// ---------------- compress A-build from fused qkv: Ak/Av[h][128][4096] bf16 ----------------
__global__ __launch_bounds__(256) void abuild_kernel(const float* __restrict__ qkv,
                                                     const float* __restrict__ pe,
                                                     unsigned short* __restrict__ Ak,
                                                     unsigned short* __restrict__ Av) {
  const size_t u = (size_t)blockIdx.x * 256 + threadIdx.x;  // < 4*128*4096
  const int h = (int)(u >> 19);
  const int rem = (int)(u & 524287);
  const int n = rem >> 12;
  const int e = rem & 4095;
  const int s = e >> 7;
  const int d = e & 127;
  int row = n * CKST + s; if (row > SEQ - 1) row = SEQ - 1;  // pad row (n=127 unused)
  const float* base = qkv + (size_t)row * NQKV + h * DH + d;
  Ak[u] = f2bf(base[HID] + pe[((size_t)h * CKS + s) * DH + d]);
  Av[u] = f2bf(base[HID + NHKV * DH]);
}

// ---------------- compress GEMM: split-K 16 chunks, z = mat*64 + h*16 + kc, glds staging ---------
__global__ __launch_bounds__(256) void compress_gemm(const unsigned short* __restrict__ Ak,
                                                     const unsigned short* __restrict__ Av,
                                                     const unsigned short* __restrict__ WckT,
                                                     const unsigned short* __restrict__ WcvT,
                                                     float* __restrict__ Cpart) {
  __shared__ __align__(16) unsigned short As[2][128 * 32];
  __shared__ __align__(16) unsigned short Bs[2][128 * 32];
  const int z = blockIdx.x;
  const int mat = z >> 6;
  const int h = (z >> 4) & 3;
  const int kc = z & 15;
  const unsigned short* A  = (mat ? Av : Ak)     + (size_t)h * 128 * CKD;
  const unsigned short* Bt = (mat ? WcvT : WckT) + (size_t)h * DH * CKD;
  float* Cout = Cpart + (size_t)z * 128 * 128;
  const int t = threadIdx.x;
  const int w = t >> 6, lane = t & 63, col = lane & 15, quad = lane >> 4;
  const int uA0 = (w * 2 + 0) * 64 + lane;
  const int uA1 = (w * 2 + 1) * 64 + lane;
  const int r0 = uA0 >> 2, e0 = (uA0 & 3) ^ ((r0 >> 1) & 3);
  const int r1 = uA1 >> 2, e1 = (uA1 & 3) ^ ((r1 >> 1) & 3);
  const int kbase = kc * 256;
  const unsigned short* gA0 = A + (size_t)r0 * CKD + kbase + e0 * 8;
  const unsigned short* gA1 = A + (size_t)r1 * CKD + kbase + e1 * 8;
  const unsigned short* gB0 = Bt + (size_t)r0 * CKD + kbase + e0 * 8;
  const unsigned short* gB1 = Bt + (size_t)r1 * CKD + kbase + e1 * 8;
  f32x4 acc[2][8];
#pragma unroll
  for (int mi = 0; mi < 2; ++mi)
#pragma unroll
    for (int ni = 0; ni < 8; ++ni) acc[mi][ni] = f32x4{0.f, 0.f, 0.f, 0.f};
  auto stage = [&](int s) {
    const int k0 = s * 32;
    const int b = s & 1;
    gload_lds16(gA0 + k0, &As[b][(w * 2 + 0) * 512]);
    gload_lds16(gA1 + k0, &As[b][(w * 2 + 1) * 512]);
    gload_lds16(gB0 + k0, &Bs[b][(w * 2 + 0) * 512]);
    gload_lds16(gB1 + k0, &Bs[b][(w * 2 + 1) * 512]);
  };
  stage(0);
  for (int s = 0; s < 8; ++s) {
    __syncthreads();
    if (s + 1 < 8) stage(s + 1);
    const unsigned short* as = As[s & 1];
    const unsigned short* bs = Bs[s & 1];
    short8 af[2], bfr[8];
#pragma unroll
    for (int mi = 0; mi < 2; ++mi) {
      const int row = w * 32 + mi * 16 + col;
      af[mi] = *(const short8*)&as[(row * 4 + (quad ^ ((row >> 1) & 3))) * 8];
    }
#pragma unroll
    for (int ni = 0; ni < 8; ++ni) {
      const int row = ni * 16 + col;
      bfr[ni] = *(const short8*)&bs[(row * 4 + (quad ^ ((row >> 1) & 3))) * 8];
    }
#pragma unroll
    for (int mi = 0; mi < 2; ++mi)
#pragma unroll
      for (int ni = 0; ni < 8; ++ni)
        acc[mi][ni] = __builtin_amdgcn_mfma_f32_16x16x32_bf16(af[mi], bfr[ni], acc[mi][ni], 0, 0, 0);
  }
#pragma unroll
  for (int mi = 0; mi < 2; ++mi)
#pragma unroll
    for (int ni = 0; ni < 8; ++ni)
#pragma unroll
      for (int r = 0; r < 4; ++r)
        Cout[(size_t)(w * 32 + mi * 16 + quad * 4 + r) * 128 + ni * 16 + col] = acc[mi][ni][r];
}

// ---------------- compress reduce (16 chunks) + fused ck-RoPE -> ckbf / cvbf ----------------
__global__ __launch_bounds__(256) void compress_reduce_rope(const float* __restrict__ Cpart,
                                                            unsigned short* __restrict__ ckbf,
                                                            unsigned short* __restrict__ cvbf) {
  const unsigned u = blockIdx.x * 256 + threadIdx.x;  // < 32768 + 65536
  if (u < 32768) {  // ck with rope: (h, n, d<64)
    const int h = u >> 13;
    const int rem = u & 8191;
    const int n = rem >> 6;
    const int d = rem & 63;
    const size_t b0 = ((size_t)(h * 16) << 14) + n * 128 + d;
    float x1 = 0.f, x2 = 0.f;
#pragma unroll
    for (int kc = 0; kc < 16; ++kc) {
      x1 += Cpart[b0 + (size_t)kc * 16384];
      x2 += Cpart[b0 + 64 + (size_t)kc * 16384];
    }
    float inv = powf(10000.f, -(float)d / 64.f);
    float ang = (float)(n * CKST) * inv;
    float c, s;
    sincosf(ang, &s, &c);
    const size_t o = ((size_t)n * NHKV + h) * DH + d;
    ckbf[o]      = f2bf(x1 * c - x2 * s);
    ckbf[o + 64] = f2bf(x2 * c + x1 * s);
  } else {  // cv: (h, n, d)
    const unsigned u2 = u - 32768;
    const int h = u2 >> 14;
    const int rem = u2 & 16383;
    const size_t b0 = ((size_t)(64 + h * 16) << 14) + rem;
    float s = 0.f;
#pragma unroll
    for (int kc = 0; kc < 16; ++kc) s += Cpart[b0 + (size_t)kc * 16384];
    const int n = rem >> 7, d = rem & 127;
    cvbf[((size_t)n * NHKV + h) * DH + d] = f2bf(s);
  }
}

// ---------------- gate = sigmoid(x @ Wg) ----------------
__global__ __launch_bounds__(128) void gate_kernel(const float* __restrict__ x,
                                                   const float* __restrict__ Wg,
                                                   float* __restrict__ gate) {
  const int i = blockIdx.x;
  const int t = threadIdx.x;
  float a0 = 0.f, a1 = 0.f, a2 = 0.f;
  for (int kk = t; kk < HID; kk += 128) {
    float xv = x[(size_t)i * HID + kk];
    a0 += xv * Wg[kk * 3 + 0];
    a1 += xv * Wg[kk * 3 + 1];
    a2 += xv * Wg[kk * 3 + 2];
  }
#pragma unroll
  for (int s = 1; s < 64; s <<= 1) {
    a0 += __shfl_xor(a0, s);
    a1 += __shfl_xor(a1, s);
    a2 += __shfl_xor(a2, s);
  }
  __shared__ float part[2][3];
  if ((t & 63) == 0) { part[t >> 6][0] = a0; part[t >> 6][1] = a1; part[t >> 6][2] = a2; }
  __syncthreads();
  if (t == 0) {
    gate[i * 3 + 0] = 1.f / (1.f + expf(-(part[0][0] + part[1][0])));
    gate[i * 3 + 1] = 1.f / (1.f + expf(-(part[0][1] + part[1][1])));
    gate[i * 3 + 2] = 1.f / (1.f + expf(-(part[0][2] + part[1][2])));
  }
}

// ---------------- RoPE (reads fused qkv, stride NQKV) ----------------
__global__ __launch_bounds__(64) void rope_q_kernel(const float* __restrict__ qkv,
                                                    unsigned short* __restrict__ qbf) {
  const int rh = blockIdx.x;
  const int r = rh >> 4;
  const int hq = rh & 15;
  const int t = threadIdx.x;
  const float* p = qkv + (size_t)r * NQKV + hq * DH;
  float x1 = p[t], x2 = p[t + 64];
  float inv = powf(10000.f, -(float)t / 64.f);
  float ang = (float)r * inv;
  float c, s;
  sincosf(ang, &s, &c);
  qbf[(size_t)rh * DH + t]      = f2bf(x1 * c - x2 * s);
  qbf[(size_t)rh * DH + t + 64] = f2bf(x2 * c + x1 * s);
}
__global__ __launch_bounds__(64) void rope_k_kernel(const float* __restrict__ qkv,
                                                    unsigned short* __restrict__ kbf) {
  const int rh = blockIdx.x;
  const int r = rh >> 2;
  const int h = rh & 3;
  const int t = threadIdx.x;
  const float* p = qkv + (size_t)r * NQKV + HID + h * DH;
  float x1 = p[t], x2 = p[t + 64];
  float inv = powf(10000.f, -(float)t / 64.f);
  float ang = (float)r * inv;
  float c, s;
  sincosf(ang, &s, &c);
  kbf[(size_t)rh * DH + t]      = f2bf(x1 * c - x2 * s);
  kbf[(size_t)rh * DH + t + 64] = f2bf(x2 * c + x1 * s);
}
// ---------------- V transpose: qkv v-part [i][h*128+d] -> vT[h][d][i] bf16 ----------------
__global__ __launch_bounds__(256) void vtrans_kernel(const float* __restrict__ qkv,
                                                     unsigned short* __restrict__ vT) {
  __shared__ float tile[32][33];
  const int tx = threadIdx.x, ty = threadIdx.y;  // 32 x 8
  const int ix = blockIdx.x * 32;   // seq
  const int dx = blockIdx.y * 32;   // d
  const int h = blockIdx.z;
#pragma unroll
  for (int r = 0; r < 4; ++r)
    tile[ty + 8 * r][tx] = qkv[(size_t)(ix + ty + 8 * r) * NQKV + HID + NHKV * DH + h * DH + dx + tx];
  __syncthreads();
#pragma unroll
  for (int r = 0; r < 4; ++r)
    vT[(size_t)(h * DH + dx + ty + 8 * r) * SEQ + ix + tx] = f2bf(tile[tx][ty + 8 * r]);
}

// ---------------- MFMA compressed attention + pscore + top-k bitmask ----------------
constexpr int CSTR = 136;
__global__ __launch_bounds__(256) void cmp_attn_mfma(const unsigned short* __restrict__ qbf,
                                                     const unsigned short* __restrict__ ckbf,
                                                     const unsigned short* __restrict__ cvbf,
                                                     unsigned short* __restrict__ cmpobf,
                                                     unsigned* __restrict__ smask) {
  __shared__ __align__(16) unsigned short cks[64 * CSTR];
  __shared__ __align__(16) unsigned short cvts[128 * CSTR];
  __shared__ __align__(16) unsigned short Ps[4][16 * CSTR];
  __shared__ float pscore[16][132];
  const int h = blockIdx.x & 3;
  const int i0 = (blockIdx.x >> 2) * 16;
  const int t = threadIdx.x;
  const int w = t >> 6;
  const int lane = t & 63;
  const int col = lane & 15;
  const int quad = lane >> 4;
  const int iq = i0 + 4 * w + quad;

  short8 qf[4];
  {
    const int qi = i0 + 4 * w + (col >> 2);
    const int g = col & 3;
    const unsigned short* qp = qbf + ((size_t)qi * NHQ + h * GQ + g) * DH + quad * 8;
#pragma unroll
    for (int dc = 0; dc < 4; ++dc) qf[dc] = *(const short8*)(qp + dc * 32);
  }
  if (t < 64) pscore[t >> 2][128 + (t & 3)] = 0.f;
  const int jmax = (iq >= CKS - 1) ? ((iq - (CKS - 1)) >> 4) : -1;

  float sreg[8][4];
  for (int ch = 0; ch < 2; ++ch) {
    if (ch) __syncthreads();
    {
      const int r = t >> 2, c0 = (t & 3) * 32;
      const unsigned short* src = ckbf + ((size_t)(ch * 64 + r) * NHKV + h) * DH + c0;
#pragma unroll
      for (int u = 0; u < 4; ++u)
        *(short8*)&cks[r * CSTR + c0 + u * 8] = *(const short8*)(src + u * 8);
    }
    if (ch == 0) {
      const int j = t >> 1, d0 = (t & 1) * 64;
      const unsigned short* vsrc = cvbf + ((size_t)j * NHKV + h) * DH + d0;
#pragma unroll
      for (int u = 0; u < 16; ++u) {
        if (j == 127) {
#pragma unroll
          for (int dd = 0; dd < 4; ++dd) cvts[(d0 + u * 4 + dd) * CSTR + j] = 0;
        } else {
          const unsigned short* vv = vsrc + u * 4;
#pragma unroll
          for (int dd = 0; dd < 4; ++dd) cvts[(d0 + u * 4 + dd) * CSTR + j] = vv[dd];
        }
      }
    }
    __syncthreads();
#pragma unroll
    for (int tt = 0; tt < 4; ++tt) {
      f32x4 s = f32x4{0.f, 0.f, 0.f, 0.f};
#pragma unroll
      for (int dc = 0; dc < 4; ++dc)
        s = __builtin_amdgcn_mfma_f32_16x16x32_bf16(
            qf[dc], *(const short8*)&cks[(tt * 16 + col) * CSTR + dc * 32 + quad * 8], s, 0, 0, 0);
#pragma unroll
      for (int r = 0; r < 4; ++r) sreg[ch * 4 + tt][r] = s[r];
    }
  }

#pragma unroll
  for (int r = 0; r < 4; ++r) {
    float mx = -INFINITY;
#pragma unroll
    for (int tt = 0; tt < 8; ++tt) {
      const float val = (tt * 16 + col <= jmax) ? sreg[tt][r] * SCALE : -INFINITY;
      sreg[tt][r] = val;
      mx = fmaxf(mx, val);
    }
    mx = fmaxf(mx, __shfl_xor(mx, 1));
    mx = fmaxf(mx, __shfl_xor(mx, 2));
    mx = fmaxf(mx, __shfl_xor(mx, 4));
    mx = fmaxf(mx, __shfl_xor(mx, 8));
    float l = 0.f;
#pragma unroll
    for (int tt = 0; tt < 8; ++tt) {
      const float p = (sreg[tt][r] == -INFINITY) ? 0.f : __expf(sreg[tt][r] - mx);
      sreg[tt][r] = p;
      l += p;
    }
    l += __shfl_xor(l, 1); l += __shfl_xor(l, 2); l += __shfl_xor(l, 4); l += __shfl_xor(l, 8);
    const float rden = 1.f / fmaxf(l, 1e-20f);
#pragma unroll
    for (int tt = 0; tt < 8; ++tt) {
      const float pn = sreg[tt][r] * rden;
      sreg[tt][r] = pn;
      Ps[w][(quad * 4 + r) * CSTR + tt * 16 + col] = f2bf(pn);
    }
  }
#pragma unroll
  for (int tt = 0; tt < 8; ++tt)
    pscore[4 * w + quad][tt * 16 + col] = sreg[tt][0] + sreg[tt][1] + sreg[tt][2] + sreg[tt][3];

  f32x4 acc[8];
#pragma unroll
  for (int dt = 0; dt < 8; ++dt) acc[dt] = f32x4{0.f, 0.f, 0.f, 0.f};
#pragma unroll
  for (int kt = 0; kt < 4; ++kt) {
    short8 ap = *(const short8*)&Ps[w][col * CSTR + kt * 32 + quad * 8];
#pragma unroll
    for (int dt = 0; dt < 8; ++dt)
      acc[dt] = __builtin_amdgcn_mfma_f32_16x16x32_bf16(
          ap, *(const short8*)&cvts[(dt * 16 + col) * CSTR + kt * 32 + quad * 8], acc[dt], 0, 0, 0);
  }
#pragma unroll
  for (int dt = 0; dt < 8; ++dt)
#pragma unroll
    for (int r = 0; r < 4; ++r)
      cmpobf[((size_t)iq * NHQ + h * GQ + r) * DH + dt * 16 + col] = f2bf(acc[dt][r]);

  __syncthreads();
  if (t < 16) {
    const int i = i0 + t;
    const int qblk = i / BSZ;
    const float offw[5] = {1.f, 2.f, 2.f, 2.f, 1.f};
    float tmp[NBLK];
    for (int b = 0; b < NBLK; ++b) {
      float s = 0.f;
#pragma unroll
      for (int o = 0; o < 5; ++o) s += pscore[t][b * MBB + o] * offw[o];
      const bool causal = (b <= qblk);
      const bool forced = (b < 1) || ((b > qblk - 2) && causal);
      tmp[b] = causal ? (forced ? INFINITY : s) : -INFINITY;
    }
    unsigned msk = 0;
    for (int s = 0; s < NTOP; ++s) {
      int best = -1;
      float bv = -INFINITY;
      for (int b = 0; b < NBLK; ++b)
        if (tmp[b] > bv) { bv = tmp[b]; best = b; }
      if (best >= 0) { msk |= (1u << best); tmp[best] = -INFINITY; }
    }
    smask[(size_t)i * NHKV + h] = msk;
  }
}

// ------- dual-mask flash attention: 32-key tiles, K+V double-buffered, 36KB LDS -------
__global__ __launch_bounds__(256) void nsa_attn_kernel(
    const unsigned short* __restrict__ qbf,
    const unsigned short* __restrict__ kbf,
    const unsigned short* __restrict__ vT,
    const unsigned* __restrict__ smask,
    const float* __restrict__ gate,
    const unsigned short* __restrict__ cmpo,
    unsigned short* __restrict__ outc) {
  __shared__ __align__(16) unsigned short Ks[2][32 * 128];  // 2 x 8 KB
  __shared__ __align__(16) unsigned short Vs[2][128 * 32];  // 2 x 8 KB
  __shared__ __align__(16) unsigned short Ps[4][16 * 32];   // 4 KB (per-wave, reused sel/win)
  const int bx = blockIdx.x;
  const int qt = 127 - (bx >> 2);   // big-work blocks first
  const int h = bx & 3;
  const int i0 = qt * 16;
  const int t = threadIdx.x;
  const int w = t >> 6;
  const int lane = t & 63;
  const int col = lane & 15;
  const int quad = lane >> 4;
  const int i0w = i0 + w * 4;
  const int i_lane = i0w + quad;

  short8 qf[4];
  {
    const int qi = i0w + (col >> 2);
    const int g = col & 3;
    const unsigned short* qp = qbf + (((size_t)qi * NHQ) + h * 4 + g) * DH + quad * 8;
#pragma unroll
    for (int dc = 0; dc < 4; ++dc) qf[dc] = *(const short8*)(qp + dc * 32);
  }
  const unsigned mymask = smask[(size_t)i_lane * NHKV + h];

  // 64-bit tile mask at 32-key granularity: selection blocks expand x2, plus window range
  unsigned long long bmask;
  {
    unsigned mm = smask[(size_t)(i0 + col) * NHKV + h];
    mm |= __shfl_xor(mm, 1); mm |= __shfl_xor(mm, 2);
    mm |= __shfl_xor(mm, 4); mm |= __shfl_xor(mm, 8);
    unsigned long long s = mm;
    s = (s | (s << 16)) & 0x0000FFFF0000FFFFull;
    s = (s | (s << 8))  & 0x00FF00FF00FF00FFull;
    s = (s | (s << 4))  & 0x0F0F0F0F0F0F0F0Full;
    s = (s | (s << 2))  & 0x3333333333333333ull;
    s = (s | (s << 1))  & 0x5555555555555555ull;
    unsigned long long sel64 = s | (s << 1);
    const int whi = (i0 + 15) >> 5;
    int wl = i0 - WINW; wl = (wl < 0) ? 0 : (wl >> 5);
    const unsigned long long hib = (whi >= 63) ? ~0ull : ((1ull << (whi + 1)) - 1ull);
    bmask = sel64 | (hib & ~((1ull << wl) - 1ull));
  }

  f32x4 accS[8], accW[8];
#pragma unroll
  for (int dt = 0; dt < 8; ++dt) { accS[dt] = f32x4{0.f,0.f,0.f,0.f}; accW[dt] = f32x4{0.f,0.f,0.f,0.f}; }
  float mS[4], mW[4], lS[4], lW[4];
#pragma unroll
  for (int r = 0; r < 4; ++r) { mS[r] = -INFINITY; mW[r] = -INFINITY; lS[r] = 0.f; lW[r] = 0.f; }

  // async staging, swizzled chunk layout
  auto stageK = [&](int b, int kb) {
#pragma unroll
    for (int qq = 0; qq < 2; ++qq) {
      const int q = w * 2 + qq;
      const int u = q * 64 + lane;
      const int r = u >> 4;
      const int c = (u & 15) ^ (r & 7);
      const unsigned short* g = kbf + ((size_t)((b * 32 + r) * NHKV + h)) * DH + c * 8;
      gload_lds16(g, &Ks[kb][q * 512]);
    }
  };
  auto stageV = [&](int b, int kb) {
#pragma unroll
    for (int qq = 0; qq < 2; ++qq) {
      const int q = w * 2 + qq;
      const int u = q * 64 + lane;
      const int d = u >> 2;
      const int c = (u & 3) ^ (d & 3);
      const unsigned short* g = vT + ((size_t)(h * DH + d)) * SEQ + b * 32 + c * 8;
      gload_lds16(g, &Vs[kb][q * 512]);
    }
  };

  unsigned long long tmw = bmask;
  int cur = __builtin_ctzll(tmw);   // bmask nonzero (block 0 forced)
  tmw &= tmw - 1;
  int buf = 0;
  stageK(cur, 0);
  stageV(cur, 0);
  while (cur >= 0) {
    int nxt = -1;
    if (tmw) { nxt = (int)__builtin_ctzll(tmw); tmw &= tmw - 1; }
    __syncthreads();                 // buf staged; prev compute (on buf^1) done
    if (nxt >= 0) { stageK(nxt, buf ^ 1); stageV(nxt, buf ^ 1); }

    const int j0 = cur * 32;
    const bool wact = (j0 <= i0w + 3);
    const bool selbit = wact && ((mymask >> (cur >> 1)) & 1u);
    const bool selAny = (__ballot(selbit) != 0ull);
    const bool winAny = wact && (j0 + 31 >= i0w - WINW);

    if (selAny || winAny) {
      f32x4 sc[2];
#pragma unroll
      for (int kt = 0; kt < 2; ++kt) {
        f32x4 ss = f32x4{0.f, 0.f, 0.f, 0.f};
        const int row = kt * 16 + col;
#pragma unroll
        for (int dc = 0; dc < 4; ++dc) {
          short8 kf = *(const short8*)&Ks[buf][row * 128 + (((dc * 4 + quad) ^ (row & 7)) << 3)];
          ss = __builtin_amdgcn_mfma_f32_16x16x32_bf16(qf[dc], kf, ss, 0, 0, 0);
        }
        sc[kt] = ss;
      }
      const int jA = j0 + col, jB = j0 + 16 + col;

      auto softmax_p = [&](bool forsel, float* mrun, float* lrun, f32x4* acc) {
#pragma unroll
        for (int r = 0; r < 4; ++r) {
          const bool aA = (jA <= i_lane) && (forsel ? selbit : (jA >= i_lane - WINW));
          const bool aB = (jB <= i_lane) && (forsel ? selbit : (jB >= i_lane - WINW));
          float v0 = aA ? sc[0][r] * SCALE : -INFINITY;
          float v1 = aB ? sc[1][r] * SCALE : -INFINITY;
          float tmax = fmaxf(v0, v1);
          tmax = fmaxf(tmax, __shfl_xor(tmax, 1));
          tmax = fmaxf(tmax, __shfl_xor(tmax, 2));
          tmax = fmaxf(tmax, __shfl_xor(tmax, 4));
          tmax = fmaxf(tmax, __shfl_xor(tmax, 8));
          const float mn = fmaxf(mrun[r], tmax);
          const float a = (mn == -INFINITY) ? 1.f : __expf(mrun[r] - mn);
          const float p0 = aA ? __expf(v0 - mn) : 0.f;
          const float p1 = aB ? __expf(v1 - mn) : 0.f;
          lrun[r] = lrun[r] * a + p0 + p1;
          mrun[r] = mn;
#pragma unroll
          for (int dt = 0; dt < 8; ++dt) acc[dt][r] *= a;
          const int m = quad * 4 + r;
          Ps[w][m * 32 + ((((col >> 3)) ^ (m & 3)) << 3) + (col & 7)]     = f2bf(p0);
          Ps[w][m * 32 + (((2 + (col >> 3)) ^ (m & 3)) << 3) + (col & 7)] = f2bf(p1);
        }
      };
      auto pv = [&](f32x4* acc) {
        short8 ap = *(const short8*)&Ps[w][col * 32 + ((quad ^ (col & 3)) << 3)];
#pragma unroll
        for (int dt = 0; dt < 8; ++dt) {
          const int rv = dt * 16 + col;
          short8 vfr = *(const short8*)&Vs[buf][rv * 32 + ((quad ^ (rv & 3)) << 3)];
          acc[dt] = __builtin_amdgcn_mfma_f32_16x16x32_bf16(ap, vfr, acc[dt], 0, 0, 0);
        }
      };

      if (selAny) { softmax_p(true, mS, lS, accS); pv(accS); }
      if (winAny) { softmax_p(false, mW, lW, accW); pv(accW); }
    }
    cur = nxt;
    buf ^= 1;
  }

  // epilogue
#pragma unroll
  for (int r = 0; r < 4; ++r) {
    float v = lS[r];
    v += __shfl_xor(v, 1); v += __shfl_xor(v, 2); v += __shfl_xor(v, 4); v += __shfl_xor(v, 8);
    lS[r] = v;
    float u = lW[r];
    u += __shfl_xor(u, 1); u += __shfl_xor(u, 2); u += __shfl_xor(u, 4); u += __shfl_xor(u, 8);
    lW[r] = u;
  }
  const float g0 = gate[i_lane * 3 + 0];
  const float g1 = gate[i_lane * 3 + 1];
  const float g2 = gate[i_lane * 3 + 2];
#pragma unroll
  for (int r = 0; r < 4; ++r) {
    const size_t base = ((size_t)i_lane * NHQ + h * 4 + r) * DH;
    const float rls = g1 / lS[r];
    const float rlw = g2 / lW[r];
#pragma unroll
    for (int dt = 0; dt < 8; ++dt) {
      const size_t o = base + dt * 16 + col;
      outc[o] = f2bf(g0 * bf2f(cmpo[o]) + rls * accS[dt][r] + rlw * accW[dt][r]);
    }
  }
}

// ---------------- launcher ----------------
extern "C" void kernel_launch(void* const* d_in, const int* in_sizes, int n_in,
                              void* d_out, int out_size, void* d_ws, size_t ws_size,
                              hipStream_t stream) {
  const float* x   = (const float*)d_in[0];
  const float* Wq  = (const float*)d_in[2];
  const float* Wk  = (const float*)d_in[3];
  const float* Wv  = (const float*)d_in[4];
  const float* Wo  = (const float*)d_in[5];
  const float* Wck = (const float*)d_in[6];
  const float* Wcv = (const float*)d_in[7];
  const float* pe  = (const float*)d_in[8];
  const float* Wg  = (const float*)d_in[9];
  float* out = (float*)d_out;

  unsigned char* p = (unsigned char*)d_ws;
  auto alloc = [&](size_t bytes) { void* r = p; p += (bytes + 255) & ~(size_t)255; return r; };
  float* qkv  = (float*)alloc((size_t)SEQ * NQKV * 4);        // 24MB; later hosts WoT + combbf
  float* gbuf = (float*)alloc((size_t)SEQ * 4 * 4);
  unsigned* smask = (unsigned*)alloc((size_t)SEQ * NHKV * 4);
  unsigned short* ckbf = (unsigned short*)alloc((size_t)128 * NHKV * DH * 2);
  unsigned short* cvbf = (unsigned short*)alloc((size_t)128 * NHKV * DH * 2);
  unsigned short* xbf  = (unsigned short*)alloc((size_t)SEQ * HID * 2);        // 8MB; -> Ak/Av -> cmpobf
  unsigned short* WqkvT = (unsigned short*)alloc((size_t)NQKV * HID * 2);      // 12MB; -> Cpart -> qbf/krbf/vT
  unsigned short* WckT = (unsigned short*)alloc((size_t)NHKV * DH * CKD * 2);  // 4MB
  unsigned short* WcvT = (unsigned short*)alloc((size_t)NHKV * DH * CKD * 2);  // 4MB
  unsigned short* WoT    = (unsigned short*)qkv;                                // 8MB
  unsigned short* combbf = (unsigned short*)qkv + (size_t)NHQ * DH * HID;       // next 8MB
  unsigned short* Ak     = xbf;
  unsigned short* Av     = xbf + (size_t)NHKV * 128 * CKD;
  unsigned short* cmpobf = xbf;
  float* Cpart = (float*)WqkvT;                                  // 8MB over future qbf (dead weights)
  unsigned short* qbf  = WqkvT;                                  // 8MB
  unsigned short* krbf = WqkvT + (size_t)HID * HID;              // 2MB
  unsigned short* vT   = WqkvT + (size_t)(HID + NHKV * DH) * HID;// 2MB

  // convert / transpose weights + x
  conv_bf_kernel<<<(SEQ * HID) / 256, 256, 0, stream>>>(x, xbf);
  transpose_bf_kernel<<<dim3(HID / 32, HID / 32), dim3(32, 8), 0, stream>>>(Wq, WqkvT, HID, HID);
  transpose_bf_kernel<<<dim3((NHKV * DH) / 32, HID / 32), dim3(32, 8), 0, stream>>>(Wk, WqkvT + (size_t)HID * HID, HID, NHKV * DH);
  transpose_bf_kernel<<<dim3((NHKV * DH) / 32, HID / 32), dim3(32, 8), 0, stream>>>(Wv, WqkvT + (size_t)(HID + NHKV * DH) * HID, HID, NHKV * DH);
  transpose_bf_kernel<<<dim3(DH / 32, CKD / 32, NHKV), dim3(32, 8), 0, stream>>>(Wck, WckT, CKD, DH);
  transpose_bf_kernel<<<dim3(DH / 32, CKD / 32, NHKV), dim3(32, 8), 0, stream>>>(Wcv, WcvT, CKD, DH);
  // fused q/k/v projection
  gemm_bf16_128<<<dim3(NQKV / 128, SEQ / 128), 256, 0, stream>>>(xbf, WqkvT, qkv, SEQ, NQKV, HID);
  gate_kernel<<<SEQ, 128, 0, stream>>>(x, Wg, gbuf);
  // compression as GEMM (A-build overwrites dead xbf; Cpart overlays dead WqkvT weights)
  abuild_kernel<<<(NHKV * 128 * CKD) / 256, 256, 0, stream>>>(qkv, pe, Ak, Av);
  compress_gemm<<<128, 256, 0, stream>>>(Ak, Av, WckT, WcvT, Cpart);
  compress_reduce_rope<<<(32768 + 65536) / 256, 256, 0, stream>>>(Cpart, ckbf, cvbf);
  // RoPE + V transpose (overwrite WqkvT/Cpart region after reduce)
  rope_q_kernel<<<SEQ * NHQ, 64, 0, stream>>>(qkv, qbf);
  rope_k_kernel<<<SEQ * NHKV, 64, 0, stream>>>(qkv, krbf);
  vtrans_kernel<<<dim3(SEQ / 32, DH / 32, NHKV), dim3(32, 8), 0, stream>>>(qkv, vT);
  // Wo transpose into dead qkv region (after all qkv consumers)
  transpose_bf_kernel<<<dim3(HID / 32, (NHQ * DH) / 32), dim3(32, 8), 0, stream>>>(Wo, WoT, NHQ * DH, HID);
  // compressed attention + selection
  cmp_attn_mfma<<<(SEQ / 16) * NHKV, 256, 0, stream>>>(qbf, ckbf, cvbf, cmpobf, smask);
  // selected + window attention + gated combine
  nsa_attn_kernel<<<(SEQ / 16) * NHKV, 256, 0, stream>>>(qbf, krbf, vT, smask, gbuf, cmpobf, combbf);
  // output projection
  gemm_bf16_128<<<dim3(HID / 128, SEQ / 128), 256, 0, stream>>>(combbf, WoT, out, SEQ, HID, NHQ * DH);
}